// Round 4
// baseline (250.512 us; speedup 1.0000x reference)
//
#include <hip/hip_runtime.h>

#define H_ 1080
#define W_ 1920
#define S_ 2000
#define C_ 8
#define HW_ (H_*W_)
#define NQ  (HW_/4)      // 518400 pixel quads
#define ROWD 17          // dwords per packed table row (29 bf16 + pad = 34 u16)
#define TABD (S_*ROWD)   // 34000 dwords = 136 KB
#define TAB4 (TABD/4)    // 8500 uint4

typedef unsigned int  u32;
typedef unsigned short u16;

// round-to-nearest-even f32 -> bf16 (finite inputs)
__device__ __forceinline__ u16 f2bf(float f){
  union { float f; u32 u; } a; a.f = f;
  return (u16)((a.u + 0x7FFFu + ((a.u >> 16) & 1u)) >> 16);
}
__device__ __forceinline__ float bf2f(u32 lo16){
  union { u32 u; float f; } a; a.u = lo16 << 16;
  return a.f;
}

// Kernel 1: per superpixel, compute the 29 final values, pack as bf16 into
// 17-dword rows in d_ws.  Row layout (u16 index):
//   [0] = preseg label; [1+4*(j-1)+{0,1,2,3}] = kd[j], knn_contrast[j],
//   cd[j], cent_contrast[j] for j=1..7;  pad to 34 u16.
__global__ void build_table_k(const int* __restrict__ knn_pred,
                              const float* __restrict__ knn_dist,
                              const float* __restrict__ cent_dist,
                              u32* __restrict__ gtab){
  int s = blockIdx.x * blockDim.x + threadIdx.x;
  if (s >= S_) return;
  float kd[C_], cd[C_];
  const float4* kr = reinterpret_cast<const float4*>(knn_dist  + s * C_);
  const float4* cr = reinterpret_cast<const float4*>(cent_dist + s * C_);
  float4 a = kr[0], b = kr[1], c = cr[0], d = cr[1];
  kd[0]=a.x; kd[1]=a.y; kd[2]=a.z; kd[3]=a.w; kd[4]=b.x; kd[5]=b.y; kd[6]=b.z; kd[7]=b.w;
  cd[0]=c.x; cd[1]=c.y; cd[2]=c.z; cd[3]=c.w; cd[4]=d.x; cd[5]=d.y; cd[6]=d.z; cd[7]=d.w;

  u16 v[34];
  #pragma unroll
  for (int i = 0; i < 34; ++i) v[i] = 0;
  v[0] = f2bf((float)knn_pred[s]);
  #pragma unroll
  for (int j = 1; j < C_; ++j){
    float km = -3.0e38f, cm = -3.0e38f;
    #pragma unroll
    for (int k = 0; k < C_; ++k){
      if (k == j) continue;
      km = fmaxf(km, kd[k]);
      cm = fmaxf(cm, cd[k]);
    }
    int bix = 1 + (j - 1) * 4;
    v[bix + 0] = f2bf(kd[j]);
    v[bix + 1] = f2bf(km);
    v[bix + 2] = f2bf(cd[j]);
    v[bix + 3] = f2bf(cm);
  }
  u32* row = gtab + s * ROWD;
  #pragma unroll
  for (int dw = 0; dw < ROWD; ++dw)
    row[dw] = (u32)v[2*dw] | ((u32)v[2*dw+1] << 16);
}

// Kernel 2: stage the 136 KB table in LDS (odd dword stride 17 -> random rows
// spread over all 32 banks), then stream pixels: 4 pixels/thread, int4 spx
// load, 15 ds_read_b32 per pixel, 29 coalesced float4 plane stores.
__global__ __launch_bounds__(512) void scatter_k(const int* __restrict__ spx,
                                                 const u32* __restrict__ gtab,
                                                 float* __restrict__ out){
  __shared__ u32 tab[TABD];          // 136 KB (gfx950 LDS = 160 KB/CU)
  {
    const uint4* g4 = reinterpret_cast<const uint4*>(gtab);
    uint4* l4 = reinterpret_cast<uint4*>(tab);
    for (int k = threadIdx.x; k < TAB4; k += 512) l4[k] = g4[k];
  }
  __syncthreads();

  const int stride = gridDim.x * 512;
  for (int q = blockIdx.x * 512 + threadIdx.x; q < NQ; q += stride){
    int p = q * 4;
    int4 s4 = *reinterpret_cast<const int4*>(spx + p);
    int base0 = (s4.x - 1) * ROWD;
    int base1 = (s4.y - 1) * ROWD;
    int base2 = (s4.z - 1) * ROWD;
    int base3 = (s4.w - 1) * ROWD;

    u32 r0[15], r1[15], r2[15], r3[15];
    #pragma unroll
    for (int dw = 0; dw < 15; ++dw){
      r0[dw] = tab[base0 + dw];
      r1[dw] = tab[base1 + dw];
      r2[dw] = tab[base2 + dw];
      r3[dw] = tab[base3 + dw];
    }

    // plane m (m=0 preseg, m=1..28 attmaps): value = u16 #m of the row
    #pragma unroll
    for (int m = 0; m < 29; ++m){
      const int dw = m >> 1;
      float4 w;
      if (m & 1){
        w.x = bf2f(r0[dw] >> 16); w.y = bf2f(r1[dw] >> 16);
        w.z = bf2f(r2[dw] >> 16); w.w = bf2f(r3[dw] >> 16);
      } else {
        w.x = bf2f(r0[dw] & 0xFFFFu); w.y = bf2f(r1[dw] & 0xFFFFu);
        w.z = bf2f(r2[dw] & 0xFFFFu); w.w = bf2f(r3[dw] & 0xFFFFu);
      }
      *reinterpret_cast<float4*>(out + (size_t)m * HW_ + p) = w;
    }
  }
}

extern "C" void kernel_launch(void* const* d_in, const int* in_sizes, int n_in,
                              void* d_out, int out_size, void* d_ws, size_t ws_size,
                              hipStream_t stream)
{
  const int*   spx       = (const int*)  d_in[0];   // (1,1,H,W) int32, labels 1..S
  const int*   knn_pred  = (const int*)  d_in[1];   // (S,) int32
  const float* knn_dist  = (const float*)d_in[2];   // (S,C) f32
  const float* cent_dist = (const float*)d_in[3];   // (S,C) f32
  float* out = (float*)d_out;                       // 29*HW float32
  u32*   gtab = (u32*)d_ws;                         // 136 KB packed bf16 table

  build_table_k<<<(S_ + 255) / 256, 256, 0, stream>>>(knn_pred, knn_dist, cent_dist, gtab);
  scatter_k<<<256, 512, 0, stream>>>(spx, gtab, out);
}